// Round 1
// baseline (152.352 us; speedup 1.0000x reference)
//
#include <hip/hip_runtime.h>
#include <hip/hip_bf16.h>

// Self-attention, N=8192, C=256, fp32 in/out, bf16 MFMA internally.
// Pipeline: proj (Q,K,V bf16; V stored transposed; Q pre-scaled by log2e/16)
//           -> flash attention (Qtile=128, KV split 4-way, partials in ws)
//           -> combine (merge splits, divide by l).
//
// ws layout:  [0,4Mi) qb bf16[8192][256]
//             [4Mi,8Mi) kb bf16[8192][256]
//             [8Mi,12Mi) vt bf16[256][8192]   (transposed V)
//             [12Mi,44Mi) Opart f32[4][8192][256]
//             [44Mi,+128Ki) Mpart f32[4][8192]
//             [+128Ki,+256Ki) Lpart f32[4][8192]
// total ~44.25 MiB required.

typedef short short8 __attribute__((ext_vector_type(8)));   // 8 bf16 = 4 VGPR
typedef float f32x4 __attribute__((ext_vector_type(4)));

static __device__ __forceinline__ unsigned short f2bf(float f) {
    __hip_bfloat16 h = __float2bfloat16(f);
    return __builtin_bit_cast(unsigned short, h);
}

static __device__ __forceinline__ short8 pack8(float4 a, float4 b) {
    short8 v;
    v[0] = (short)f2bf(a.x); v[1] = (short)f2bf(a.y);
    v[2] = (short)f2bf(a.z); v[3] = (short)f2bf(a.w);
    v[4] = (short)f2bf(b.x); v[5] = (short)f2bf(b.y);
    v[6] = (short)f2bf(b.z); v[7] = (short)f2bf(b.w);
    return v;
}

// ---------------- projection: out = x @ W^T (bf16), q scaled by log2e/16 ----
// grid (128, 4), block 256. mb: 64-row x tile, nb: 64-feature W tile,
// w-loop inside reuses the staged x tile + A fragments across Wq/Wk/Wv.
__global__ __launch_bounds__(256) void proj_kernel(
    const float* __restrict__ x, const float* __restrict__ Wq,
    const float* __restrict__ Wk, const float* __restrict__ Wv,
    unsigned short* __restrict__ qb, unsigned short* __restrict__ kb,
    unsigned short* __restrict__ vt)
{
    const int mb = blockIdx.x, nb = blockIdx.y;
    __shared__ unsigned short xs[64 * 256];   // 32 KB, chunk-XOR swizzled
    __shared__ unsigned short wsh[64 * 256];  // 32 KB
    const int tid = threadIdx.x;
    const int wid = tid >> 6, lane = tid & 63;
    const int l15 = lane & 15, kg = lane >> 4;

    // stage x tile and Wq tile (fp32 -> bf16), 16B chunks, swizzle chunk^(row&7)
    for (int i = 0; i < 8; ++i) {
        int id = i * 256 + tid;
        int r = id >> 5, c = id & 31;
        {
            const float* g = x + (size_t)(mb * 64 + r) * 256 + c * 8;
            float4 f0 = *(const float4*)g, f1 = *(const float4*)(g + 4);
            *(short8*)&xs[r * 256 + ((c ^ (r & 7)) * 8)] = pack8(f0, f1);
        }
        {
            const float* g = Wq + (size_t)(nb * 64 + r) * 256 + c * 8;
            float4 f0 = *(const float4*)g, f1 = *(const float4*)(g + 4);
            *(short8*)&wsh[r * 256 + ((c ^ (r & 7)) * 8)] = pack8(f0, f1);
        }
    }
    __syncthreads();

    const int arow = wid * 16 + l15;
    short8 a[8];
#pragma unroll
    for (int ks = 0; ks < 8; ++ks)
        a[ks] = *(const short8*)&xs[arow * 256 + (((ks * 4 + kg) ^ (arow & 7)) * 8)];

    for (int w = 0; w < 3; ++w) {
        const float scale = (w == 0) ? 0.09016844005555f : 1.0f; // log2(e)/16
#pragma unroll
        for (int nt = 0; nt < 4; ++nt) {
            f32x4 acc = {0.f, 0.f, 0.f, 0.f};
            const int brow = nt * 16 + l15;
#pragma unroll
            for (int ks = 0; ks < 8; ++ks) {
                short8 b = *(const short8*)&wsh[brow * 256 + (((ks * 4 + kg) ^ (brow & 7)) * 8)];
                acc = __builtin_amdgcn_mfma_f32_16x16x32_bf16(a[ks], b, acc, 0, 0, 0);
            }
            const int gcol = nb * 64 + nt * 16 + l15;
#pragma unroll
            for (int r = 0; r < 4; ++r) {
                const int grow = mb * 64 + wid * 16 + kg * 4 + r;
                unsigned short h = f2bf(acc[r] * scale);
                if (w == 0)      qb[(size_t)grow * 256 + gcol] = h;
                else if (w == 1) kb[(size_t)grow * 256 + gcol] = h;
                else             vt[(size_t)gcol * 8192 + grow] = h;  // transposed
            }
        }
        if (w < 2) {
            __syncthreads();
            const float* Wn = (w == 0) ? Wk : Wv;
            for (int i = 0; i < 8; ++i) {
                int id = i * 256 + tid;
                int r = id >> 5, c = id & 31;
                const float* g = Wn + (size_t)(nb * 64 + r) * 256 + c * 8;
                float4 f0 = *(const float4*)g, f1 = *(const float4*)(g + 4);
                *(short8*)&wsh[r * 256 + ((c ^ (r & 7)) * 8)] = pack8(f0, f1);
            }
            __syncthreads();
        }
    }
}

// ---------------- flash attention, partials per KV-split ------------------
// grid (64, 4), block 512 (8 waves x 16 Q rows). KVB=64, 32 iters per split.
__global__ __launch_bounds__(512) void attn_kernel(
    const unsigned short* __restrict__ qb, const unsigned short* __restrict__ kb,
    const unsigned short* __restrict__ vt,
    float* __restrict__ Opart, float* __restrict__ Mpart, float* __restrict__ Lpart)
{
    __shared__ unsigned short Ks[64 * 256];    // 32 KB  K tile, swizzled
    __shared__ unsigned short Vs[256 * 64];    // 32 KB  Vt tile, swizzled
    __shared__ unsigned short Ps[8][16 * 64];  // 16 KB  per-wave P bounce
    const int qblk = blockIdx.x, split = blockIdx.y;
    const int tid = threadIdx.x, wid = tid >> 6, lane = tid & 63;
    const int l15 = lane & 15, kg = lane >> 4;
    const int qrow0 = qblk * 128 + wid * 16;

    // Q fragments (pre-scaled in proj), kept in registers: 16 rows x 256
    short8 qf[8];
#pragma unroll
    for (int ks = 0; ks < 8; ++ks)
        qf[ks] = *(const short8*)(qb + (size_t)(qrow0 + l15) * 256 + ks * 32 + kg * 8);

    f32x4 accO[16];
#pragma unroll
    for (int i = 0; i < 16; ++i) accO[i] = (f32x4){0.f, 0.f, 0.f, 0.f};
    float mrow[4], lrow[4];
#pragma unroll
    for (int r = 0; r < 4; ++r) { mrow[r] = -1e30f; lrow[r] = 0.f; }

    const int kv0 = split * 2048;
    for (int t = 0; t < 32; ++t) {
        __syncthreads();  // previous iter's reads done before restage
        // stage K tile: 64 rows x 256 bf16
#pragma unroll
        for (int i = 0; i < 4; ++i) {
            int id = i * 512 + tid;
            int r = id >> 5, c = id & 31;
            short8 v = *(const short8*)(kb + (size_t)(kv0 + t * 64 + r) * 256 + c * 8);
            *(short8*)&Ks[r * 256 + ((c ^ (r & 7)) * 8)] = v;
        }
        // stage Vt tile: 256 rows x 64 bf16
#pragma unroll
        for (int i = 0; i < 4; ++i) {
            int id = i * 512 + tid;
            int r = id >> 3, c = id & 7;
            short8 v = *(const short8*)(vt + (size_t)r * 8192 + kv0 + t * 64 + c * 8);
            *(short8*)&Vs[r * 64 + ((c ^ (r & 7)) * 8)] = v;
        }
        __syncthreads();

        // S = Q @ K^T  (exp2-domain, scale folded into Q)
        f32x4 sacc[4];
#pragma unroll
        for (int nt = 0; nt < 4; ++nt) {
            f32x4 acc = {0.f, 0.f, 0.f, 0.f};
            const int brow = nt * 16 + l15;
#pragma unroll
            for (int ks = 0; ks < 8; ++ks) {
                short8 kf = *(const short8*)&Ks[brow * 256 + (((ks * 4 + kg) ^ (brow & 7)) * 8)];
                acc = __builtin_amdgcn_mfma_f32_16x16x32_bf16(qf[ks], kf, acc, 0, 0, 0);
            }
            sacc[nt] = acc;
        }

        // online softmax per row (rows r=0..3 of this lane group)
        float pv[4][4];
#pragma unroll
        for (int r = 0; r < 4; ++r) {
            float tm = fmaxf(fmaxf(sacc[0][r], sacc[1][r]), fmaxf(sacc[2][r], sacc[3][r]));
            tm = fmaxf(tm, __shfl_xor(tm, 1));
            tm = fmaxf(tm, __shfl_xor(tm, 2));
            tm = fmaxf(tm, __shfl_xor(tm, 4));
            tm = fmaxf(tm, __shfl_xor(tm, 8));
            float mn = fmaxf(mrow[r], tm);
            float alpha = exp2f(mrow[r] - mn);
            float rs = 0.f;
#pragma unroll
            for (int nt = 0; nt < 4; ++nt) { pv[nt][r] = exp2f(sacc[nt][r] - mn); rs += pv[nt][r]; }
            rs += __shfl_xor(rs, 1);
            rs += __shfl_xor(rs, 2);
            rs += __shfl_xor(rs, 4);
            rs += __shfl_xor(rs, 8);
            lrow[r] = lrow[r] * alpha + rs;
            mrow[r] = mn;
#pragma unroll
            for (int dt = 0; dt < 16; ++dt) accO[dt][r] *= alpha;
        }

        // P (D-layout) -> LDS (swizzled) -> A-layout fragments
#pragma unroll
        for (int nt = 0; nt < 4; ++nt)
#pragma unroll
            for (int r = 0; r < 4; ++r) {
                int row = kg * 4 + r, col = nt * 16 + l15;
                Ps[wid][row * 64 + (((col >> 3) ^ (row & 7)) * 8) + (col & 7)] = f2bf(pv[nt][r]);
            }
        asm volatile("s_waitcnt lgkmcnt(0)" ::: "memory");  // wave-private: lgkm only
        short8 pa[2];
#pragma unroll
        for (int k2 = 0; k2 < 2; ++k2)
            pa[k2] = *(const short8*)&Ps[wid][l15 * 64 + (((k2 * 4 + kg) ^ (l15 & 7)) * 8)];

        // O += P @ V
#pragma unroll
        for (int dt = 0; dt < 16; ++dt) {
            const int vrow = dt * 16 + l15;
#pragma unroll
            for (int k2 = 0; k2 < 2; ++k2) {
                short8 vf = *(const short8*)&Vs[vrow * 64 + (((k2 * 4 + kg) ^ (vrow & 7)) * 8)];
                accO[dt] = __builtin_amdgcn_mfma_f32_16x16x32_bf16(pa[k2], vf, accO[dt], 0, 0, 0);
            }
        }
    }

    // partials out (un-normalized)
#pragma unroll
    for (int dt = 0; dt < 16; ++dt) {
        const int d = dt * 16 + l15;
#pragma unroll
        for (int r = 0; r < 4; ++r) {
            const int grow = qrow0 + kg * 4 + r;
            Opart[((size_t)split * 8192 + grow) * 256 + d] = accO[dt][r];
        }
    }
    if (l15 == 0) {
#pragma unroll
        for (int r = 0; r < 4; ++r) {
            const int grow = qrow0 + kg * 4 + r;
            Mpart[split * 8192 + grow] = mrow[r];
            Lpart[split * 8192 + grow] = lrow[r];
        }
    }
}

// ---------------- combine the 4 KV-split partials -------------------------
__global__ __launch_bounds__(256) void combine_kernel(
    const float* __restrict__ Opart, const float* __restrict__ Mpart,
    const float* __restrict__ Lpart, float* __restrict__ out)
{
    const int idx = blockIdx.x * 256 + threadIdx.x;  // one float4 each
    const int row = idx >> 6;
    const int d = (idx & 63) * 4;
    float m0 = Mpart[row], m1 = Mpart[8192 + row];
    float m2 = Mpart[16384 + row], m3 = Mpart[24576 + row];
    float mm = fmaxf(fmaxf(m0, m1), fmaxf(m2, m3));
    float w0 = exp2f(m0 - mm), w1 = exp2f(m1 - mm);
    float w2 = exp2f(m2 - mm), w3 = exp2f(m3 - mm);
    float l0 = Lpart[row], l1 = Lpart[8192 + row];
    float l2 = Lpart[16384 + row], l3 = Lpart[24576 + row];
    float inv = 1.0f / (l0 * w0 + l1 * w1 + l2 * w2 + l3 * w3);
    float4 o0 = *(const float4*)(Opart + ((size_t)0 * 8192 + row) * 256 + d);
    float4 o1 = *(const float4*)(Opart + ((size_t)1 * 8192 + row) * 256 + d);
    float4 o2 = *(const float4*)(Opart + ((size_t)2 * 8192 + row) * 256 + d);
    float4 o3 = *(const float4*)(Opart + ((size_t)3 * 8192 + row) * 256 + d);
    float4 r;
    r.x = (o0.x * w0 + o1.x * w1 + o2.x * w2 + o3.x * w3) * inv;
    r.y = (o0.y * w0 + o1.y * w1 + o2.y * w2 + o3.y * w3) * inv;
    r.z = (o0.z * w0 + o1.z * w1 + o2.z * w2 + o3.z * w3) * inv;
    r.w = (o0.w * w0 + o1.w * w1 + o2.w * w2 + o3.w * w3) * inv;
    *(float4*)(out + (size_t)row * 256 + d) = r;
}

extern "C" void kernel_launch(void* const* d_in, const int* in_sizes, int n_in,
                              void* d_out, int out_size, void* d_ws, size_t ws_size,
                              hipStream_t stream)
{
    const float* x  = (const float*)d_in[0];
    const float* Wq = (const float*)d_in[1];
    const float* Wk = (const float*)d_in[2];
    const float* Wv = (const float*)d_in[3];
    char* ws = (char*)d_ws;
    unsigned short* qb = (unsigned short*)(ws);
    unsigned short* kb = (unsigned short*)(ws + (4u << 20));
    unsigned short* vt = (unsigned short*)(ws + (8u << 20));
    float* Opart = (float*)(ws + (12u << 20));
    float* Mpart = (float*)(ws + (44u << 20));
    float* Lpart = (float*)(ws + (44u << 20) + (1u << 18));
    float* out = (float*)d_out;

    dim3 gA(128, 4);
    proj_kernel<<<gA, 256, 0, stream>>>(x, Wq, Wk, Wv, qb, kb, vt);
    dim3 gB(64, 4);
    attn_kernel<<<gB, 512, 0, stream>>>(qb, kb, vt, Opart, Mpart, Lpart);
    combine_kernel<<<2048, 256, 0, stream>>>(Opart, Mpart, Lpart, out);
}